// Round 2
// baseline (553.353 us; speedup 1.0000x reference)
//
#include <hip/hip_runtime.h>

// MultiIndexSelect: out[to_k[i]] = mat_k[from_k[i]], k=0..2
// L = 400000 rows per segment, D = 64 fp32 (256 B per row).
//
// Two-pass scheme exploiting that to0||to1||to2 is a full permutation of
// [0, 3L):
//   Pass 1: code[to_k[i]] = (k << 19) | from_k[i]   (4B scatter, ~5 MB, L2/L3)
//   Pass 2: walk output rows sequentially; decode code[o]; gather the
//           random 256 B source row; SEQUENTIAL nontemporal write of out[o].
// This turns the 307 MB random scatter-write into a sequential stream
// (fills measured at 6.4 TB/s) and leaves only the gather-read random.
// Pass-2 threads each handle 4 rows -> 4 independent gathers in flight (MLP).

#define L_ROWS 400000
#define N_OUT (3 * L_ROWS)          // 1,200,000 output rows
#define VEC_PER_ROW 16              // 64 floats / 4 per float4
#define CH (N_OUT / 4)              // 300,000 rows per pass-2 chunk
#define K_SHIFT 19                  // 500000 < 2^19, so from fits in 19 bits
#define SRC_MASK ((1u << K_SHIFT) - 1u)

// Native clang vector type — __builtin_nontemporal_store rejects
// HIP_vector_type<float,4> but accepts this (identical 16 B layout).
typedef float nfloat4 __attribute__((ext_vector_type(4)));

// ---------------- Pass 1: invert the permutation, pack (k, from) ----------
__global__ __launch_bounds__(256) void build_codes_kernel(
    const int* __restrict__ from0,
    const int* __restrict__ from1,
    const int* __restrict__ from2,
    const int* __restrict__ to0,
    const int* __restrict__ to1,
    const int* __restrict__ to2,
    unsigned int* __restrict__ code)
{
    int i = blockIdx.x * blockDim.x + threadIdx.x;
    if (i >= L_ROWS) return;
    // Coalesced reads of from/to; 4 B scatters land in L2/L3 (4.8 MB target).
    code[to0[i]] = (unsigned int)from0[i];
    code[to1[i]] = (unsigned int)from1[i] | (1u << K_SHIFT);
    code[to2[i]] = (unsigned int)from2[i] | (2u << K_SHIFT);
}

// ---------------- Pass 2: random gather, sequential write -----------------
__global__ __launch_bounds__(256) void gather_seq_write_kernel(
    const nfloat4* __restrict__ mat0,
    const nfloat4* __restrict__ mat1,
    const nfloat4* __restrict__ mat2,
    const unsigned int* __restrict__ code,
    nfloat4* __restrict__ out)
{
    int tid = blockIdx.x * blockDim.x + threadIdx.x;
    int col = tid & 15;          // float4 index within the row
    int rid = tid >> 4;          // row within first chunk
    if (rid >= CH) return;       // grid is exact; guard is free

    // 4 independent code loads (same cache line across the row's 16 lanes).
    unsigned int c0 = code[rid];
    unsigned int c1 = code[rid + CH];
    unsigned int c2 = code[rid + 2 * CH];
    unsigned int c3 = code[rid + 3 * CH];

    // Branchless matrix select per row.
    unsigned int k0 = c0 >> K_SHIFT, k1 = c1 >> K_SHIFT;
    unsigned int k2 = c2 >> K_SHIFT, k3 = c3 >> K_SHIFT;
    const nfloat4* p0 = (k0 == 0) ? mat0 : ((k0 == 1) ? mat1 : mat2);
    const nfloat4* p1 = (k1 == 0) ? mat0 : ((k1 == 1) ? mat1 : mat2);
    const nfloat4* p2 = (k2 == 0) ? mat0 : ((k2 == 1) ? mat1 : mat2);
    const nfloat4* p3 = (k3 == 0) ? mat0 : ((k3 == 1) ? mat1 : mat2);

    // 4 independent random 256 B gathers in flight per thread (16 B/lane).
    nfloat4 v0 = p0[(size_t)(c0 & SRC_MASK) * VEC_PER_ROW + col];
    nfloat4 v1 = p1[(size_t)(c1 & SRC_MASK) * VEC_PER_ROW + col];
    nfloat4 v2 = p2[(size_t)(c2 & SRC_MASK) * VEC_PER_ROW + col];
    nfloat4 v3 = p3[(size_t)(c3 & SRC_MASK) * VEC_PER_ROW + col];

    // Fully sequential 256 B-per-row writes; nontemporal so the streaming
    // output does not evict the 384 MB gather working set from L2/L3.
    __builtin_nontemporal_store(v0, &out[(size_t)rid * VEC_PER_ROW + col]);
    __builtin_nontemporal_store(v1, &out[(size_t)(rid + CH) * VEC_PER_ROW + col]);
    __builtin_nontemporal_store(v2, &out[(size_t)(rid + 2 * CH) * VEC_PER_ROW + col]);
    __builtin_nontemporal_store(v3, &out[(size_t)(rid + 3 * CH) * VEC_PER_ROW + col]);
}

// ---------------- Fallback: original single-pass kernel -------------------
__global__ __launch_bounds__(256) void multi_index_select_kernel(
    const float4* __restrict__ mat0,
    const float4* __restrict__ mat1,
    const float4* __restrict__ mat2,
    const int*    __restrict__ from0,
    const int*    __restrict__ from1,
    const int*    __restrict__ from2,
    const int*    __restrict__ to0,
    const int*    __restrict__ to1,
    const int*    __restrict__ to2,
    float4*       __restrict__ out)
{
    long long tid = (long long)blockIdx.x * blockDim.x + threadIdx.x;
    int row = (int)(tid >> 4);
    int col = (int)(tid & 15);
    if (row >= N_OUT) return;

    const float4* mat;
    const int* from;
    const int* to;
    int r;
    if (row < L_ROWS) {
        mat = mat0; from = from0; to = to0; r = row;
    } else if (row < 2 * L_ROWS) {
        mat = mat1; from = from1; to = to1; r = row - L_ROWS;
    } else {
        mat = mat2; from = from2; to = to2; r = row - 2 * L_ROWS;
    }

    int src = from[r];
    int dst = to[r];
    out[(size_t)dst * VEC_PER_ROW + col] = mat[(size_t)src * VEC_PER_ROW + col];
}

extern "C" void kernel_launch(void* const* d_in, const int* in_sizes, int n_in,
                              void* d_out, int out_size, void* d_ws, size_t ws_size,
                              hipStream_t stream) {
    const float4* mat0 = (const float4*)d_in[0];
    const float4* mat1 = (const float4*)d_in[1];
    const float4* mat2 = (const float4*)d_in[2];
    const int* from0 = (const int*)d_in[3];
    const int* from1 = (const int*)d_in[4];
    const int* from2 = (const int*)d_in[5];
    const int* to0   = (const int*)d_in[6];
    const int* to1   = (const int*)d_in[7];
    const int* to2   = (const int*)d_in[8];
    float4* out = (float4*)d_out;

    const size_t code_bytes = (size_t)N_OUT * sizeof(unsigned int);  // 4.8 MB

    if (ws_size >= code_bytes) {
        unsigned int* code = (unsigned int*)d_ws;

        // Pass 1: build packed inverse permutation (1563 blocks).
        build_codes_kernel<<<(L_ROWS + 255) / 256, 256, 0, stream>>>(
            from0, from1, from2, to0, to1, to2, code);

        // Pass 2: 4.8M threads, 4 rows/thread, exact grid (18750 blocks).
        const int threads2 = CH * VEC_PER_ROW;            // 4,800,000
        gather_seq_write_kernel<<<threads2 / 256, 256, 0, stream>>>(
            (const nfloat4*)mat0, (const nfloat4*)mat1, (const nfloat4*)mat2,
            code, (nfloat4*)out);
    } else {
        // Workspace too small: original single-pass gather/scatter.
        const long long total_threads = (long long)N_OUT * VEC_PER_ROW;
        const int block = 256;
        const int grid = (int)((total_threads + block - 1) / block);
        multi_index_select_kernel<<<grid, block, 0, stream>>>(
            mat0, mat1, mat2, from0, from1, from2, to0, to1, to2, out);
    }
}